// Round 10
// baseline (223.982 us; speedup 1.0000x reference)
//
#include <hip/hip_runtime.h>
#include <stdint.h>

#define T_ROWS 8192
#define IN_F 4096
#define OUT_F 4096

using i32x4 = __attribute__((ext_vector_type(4))) int;

#define GLOBAL_AS __attribute__((address_space(1)))
#define LDS_AS __attribute__((address_space(3)))

static __device__ __forceinline__ void load_lds16(const void* g, void* l) {
    __builtin_amdgcn_global_load_lds((const GLOBAL_AS uint32_t*)g,
                                     (LDS_AS uint32_t*)l, 16, 0, 0);
}

// -------- Kernel 1: fused prep: per-row int8 quant (blocks 0..8191) +
//                    ternary f32 -> int8 weight pack (blocks 8192..12287) --------
__global__ __launch_bounds__(256) void prep_kernel(const float* __restrict__ x,
                                                   int8_t* __restrict__ xq,
                                                   float* __restrict__ scales,
                                                   const float* __restrict__ w,
                                                   int8_t* __restrict__ w8) {
    if (blockIdx.x < T_ROWS) {
        const int row = blockIdx.x;
        const float* xr = x + (size_t)row * IN_F;
        const float4* xr4 = (const float4*)xr;

        float4 v[4];
        float amax = 0.0f;
#pragma unroll
        for (int i = 0; i < 4; ++i) {
            v[i] = xr4[threadIdx.x + 256 * i];
            amax = fmaxf(amax, fmaxf(fmaxf(fabsf(v[i].x), fabsf(v[i].y)),
                                     fmaxf(fabsf(v[i].z), fabsf(v[i].w))));
        }
#pragma unroll
        for (int off = 32; off; off >>= 1)
            amax = fmaxf(amax, __shfl_xor(amax, off, 64));
        __shared__ float smax[4];
        if ((threadIdx.x & 63) == 0) smax[threadIdx.x >> 6] = amax;
        __syncthreads();
        amax = fmaxf(fmaxf(smax[0], smax[1]), fmaxf(smax[2], smax[3]));

        const float act_scale = fmaxf(amax, 1e-10f) / 127.0f;
        if (threadIdx.x == 0) scales[row] = act_scale;

        int* xqr = (int*)(xq + (size_t)row * IN_F);
#pragma unroll
        for (int i = 0; i < 4; ++i) {
            int q0 = (int)fminf(fmaxf(rintf(v[i].x / act_scale), -127.0f), 127.0f);
            int q1 = (int)fminf(fmaxf(rintf(v[i].y / act_scale), -127.0f), 127.0f);
            int q2 = (int)fminf(fmaxf(rintf(v[i].z / act_scale), -127.0f), 127.0f);
            int q3 = (int)fminf(fmaxf(rintf(v[i].w / act_scale), -127.0f), 127.0f);
            int packed = (q0 & 0xff) | ((q1 & 0xff) << 8) | ((q2 & 0xff) << 16) | (q3 << 24);
            xqr[threadIdx.x + 256 * i] = packed;
        }
    } else {
        const float4* w4 = (const float4*)w;
        int* o4 = (int*)w8;
        size_t base = (size_t)(blockIdx.x - T_ROWS) * 1024 + threadIdx.x;
#pragma unroll
        for (int i = 0; i < 4; ++i) {
            size_t idx = base + 256 * i;
            float4 v = w4[idx];
            int q0 = (int)v.x, q1 = (int)v.y, q2 = (int)v.z, q3 = (int)v.w;
            o4[idx] = (q0 & 0xff) | ((q1 & 0xff) << 8) | ((q2 & 0xff) << 16) | (q3 << 24);
        }
    }
}

// -------- Kernel 2: 256x256 int8 MFMA GEMM, A via LDS / B direct from L2 --------
// C[t][o] = sum_k xq[t][k] * w8[o][k]   (NT: both row-major, K contiguous)
// 512 threads = 8 waves (2M x 4N). Per-wave output 128x64 interleaved:
//   rows = m*32 + wr*16 (m=0..7), cols = n*64 + wc*16 (n=0..3).
// A: LDS [buf 2][row 256][128B], XOR-swizzled (slot ^= row&7), gload_lds with
//    pre-swizzled per-lane source (as rounds 4-9; measured conflict-free).
//    16 ds_read_b128 + 4 gload_lds per wave per K-tile -> LDS ~1792 cyc/K-tile
//    < MFMA 2046 cyc: the serial chain is now MFMA-dominated.
// B: fragments loaded straight from w8 (global) into registers, on the L2/VMEM
//    pipe (parallel to LDS). Frag (n,ks): lane reads 16B at
//    w8[(bcol + n*64 + wc*16 + l16)*4096 + kt*128 + ks*64 + lq*16].
//    bn0 = n{0,1} (used p1,p4), bn1 = n{2,3} (used p2,p3). 8 loads/K-tile.
//    2x wr-redundancy = 64KB/K-tile/CU from L2; XCD column-slab swizzle keeps
//    each XCD's B slab at 2MB (L2-resident).
// Phases per K-tile (quadrant order (0,0),(0,1),(1,1),(1,0)):
//   p1: READ_A(MH0) ; load bn1@KT ; MFMA(0,0,bn0)
//   p2: MFMA(0,1,bn1)
//   p3: READ_A(MH1) ; stage A(buf^1 <- KN) ; fence ; MFMA(1,1,bn1)
//   p4: MFMA(1,0,bn0) ; load bn0@KN ; vmcnt(4) ; barrier
// ONE barrier per K-tile. Boundary vmcnt(4) retires the A-stages (issue order
// pinned by the p3 fence: bn1, A-stages, bn0 -> 4 outstanding = bn0 only),
// satisfying the A RAW for next p1; A WAR (reads of buf vs restage at t+1 p3)
// crosses the boundary barrier. B-load RAW is compiler-tracked (normal loads).
__global__ __launch_bounds__(512, 2) void gemm_kernel(const int8_t* __restrict__ xq,
                                                      const int8_t* __restrict__ w8,
                                                      const float* __restrict__ scales,
                                                      const float* __restrict__ bias,
                                                      const float* __restrict__ wscale_p,
                                                      float* __restrict__ out) {
    __shared__ __align__(16) int8_t As[2 * 256 * 128];  // 64 KiB (A only)

    const int tid = threadIdx.x;
    const int lane = tid & 63;
    const int w = tid >> 6;     // wave 0..7
    const int wr = w >> 2;      // 0..1
    const int wc = w & 3;       // 0..3
    const int l16 = lane & 15;
    const int lq = lane >> 4;   // 0..3

    // XCD column-slab swizzle: xcd = bid&7 owns bcol pair {2*xcd, 2*xcd+1}
    // (2MB of w8, L2-resident); brow sweeps 0..31 within the slab.
    const int orig = blockIdx.x;
    const int xcd = orig & 7;
    const int j = orig >> 3;            // 0..63
    const int brow = (j >> 1) * 256;    // 32 row tiles
    const int bcol = (xcd * 2 + (j & 1)) * 256;

    // per-lane A staging source: row +(lane>>3), K-slot (lane&7)^(lane>>3)
    const int lrow = lane >> 3;
    const int lslot = (lane & 7) ^ lrow;
    const int8_t* srcA = xq + (size_t)(brow + lrow) * IN_F + lslot * 16;

    // per-lane A fragment read pointers (ks=0 / ks=1 slots differ by ^4)
    const int sA = l16 & 7;
    const int8_t* pA0 = As + (wr * 16 + l16) * 128 + ((lq ^ sA) << 4);
    const int8_t* pA1 = As + (wr * 16 + l16) * 128 + (((lq ^ sA) ^ 4) << 4);

    // per-lane B global source (row = bcol + n*64 + wc*16 + l16, chunk lq)
    const int8_t* pBsrc = w8 + (size_t)(bcol + wc * 16 + l16) * IN_F + lq * 16;

#define STAGE_A(BUF, KT) do {                                                      \
    load_lds16(srcA + (size_t)(0 * 128 + w * 8) * IN_F + (KT) * 128,               \
               (void*)(As + (BUF) * 32768 + (0 * 16 + w) * 1024));                 \
    load_lds16(srcA + (size_t)(0 * 128 + (w + 8) * 8) * IN_F + (KT) * 128,         \
               (void*)(As + (BUF) * 32768 + (0 * 16 + w + 8) * 1024));             \
    load_lds16(srcA + (size_t)(1 * 128 + w * 8) * IN_F + (KT) * 128,               \
               (void*)(As + (BUF) * 32768 + (1 * 16 + w) * 1024));                 \
    load_lds16(srcA + (size_t)(1 * 128 + (w + 8) * 8) * IN_F + (KT) * 128,         \
               (void*)(As + (BUF) * 32768 + (1 * 16 + w + 8) * 1024));             \
} while (0)

#define READ_A(BUF, MH)                                                            \
    _Pragma("unroll") for (int m = 0; m < 4; ++m) {                                \
        ra[m][0] = *(const i32x4*)(pA0 + (BUF) * 32768 + ((MH) * 4 + m) * 4096);   \
        ra[m][1] = *(const i32x4*)(pA1 + (BUF) * 32768 + ((MH) * 4 + m) * 4096);   \
    }

#define LOAD_BN(DST, NBASE, KT)                                                    \
    _Pragma("unroll") for (int jj = 0; jj < 2; ++jj)                               \
    _Pragma("unroll") for (int ks = 0; ks < 2; ++ks)                               \
        DST[jj][ks] = *(const i32x4*)(pBsrc + (size_t)(((NBASE) + jj) * 64) * IN_F \
                                      + (KT) * 128 + ks * 64);

#define MFMA16(MH, NH, BREG) do {                                                  \
    __builtin_amdgcn_s_setprio(1);                                                 \
    _Pragma("unroll") for (int m = 0; m < 4; ++m)                                  \
    _Pragma("unroll") for (int n = 0; n < 2; ++n) {                                \
        acc[(MH) * 4 + m][(NH) * 2 + n] = __builtin_amdgcn_mfma_i32_16x16x64_i8(   \
            ra[m][0], BREG[n][0], acc[(MH) * 4 + m][(NH) * 2 + n], 0, 0, 0);       \
        acc[(MH) * 4 + m][(NH) * 2 + n] = __builtin_amdgcn_mfma_i32_16x16x64_i8(   \
            ra[m][1], BREG[n][1], acc[(MH) * 4 + m][(NH) * 2 + n], 0, 0, 0);       \
    }                                                                              \
    __builtin_amdgcn_s_setprio(0);                                                 \
} while (0)

#define FENCE asm volatile("" ::: "memory")

#define KTILE(BUF, KT, KN) do {                                                    \
    /* p1 */                                                                       \
    READ_A(BUF, 0);                                                                \
    LOAD_BN(bn1, 2, KT);                                                           \
    MFMA16(0, 0, bn0);                                                             \
    /* p2 */                                                                       \
    MFMA16(0, 1, bn1);                                                             \
    /* p3 */                                                                       \
    READ_A(BUF, 1);                                                                \
    STAGE_A((BUF) ^ 1, KN);                                                        \
    FENCE;                                                                         \
    MFMA16(1, 1, bn1);                                                             \
    /* p4 */                                                                       \
    MFMA16(1, 0, bn0);                                                             \
    LOAD_BN(bn0, 0, KN);                                                           \
    asm volatile("s_waitcnt vmcnt(4)" ::: "memory");                               \
    __builtin_amdgcn_s_barrier();                                                  \
    FENCE;                                                                         \
} while (0)

    i32x4 acc[8][4] = {};
    i32x4 ra[4][2], bn0[2][2], bn1[2][2];

    // Prologue: buf0 <- K-tile 0 (A), bn0 <- N0@K-tile 0.
    STAGE_A(0, 0);
    LOAD_BN(bn0, 0, 0);
    asm volatile("s_waitcnt vmcnt(0)" ::: "memory");
    __builtin_amdgcn_s_barrier();
    FENCE;

    for (int t = 0; t < 16; ++t) {
        const int k0 = 2 * t;
        const int k1 = 2 * t + 1;
        const int k2 = (2 * t + 2) & 31;  // wrap on last iter: dead-but-safe loads
        KTILE(0, k0, k1);
        KTILE(1, k1, k2);
    }

    // Epilogue: D mapping col = lane&15, row = lq*4 + j within each 16x16 frag.
    const float ws = wscale_p[0];
#pragma unroll
    for (int m = 0; m < 8; ++m) {
        const int row0 = brow + m * 32 + wr * 16 + lq * 4;
#pragma unroll
        for (int jj = 0; jj < 4; ++jj) {
            const int row = row0 + jj;
            const float sc = scales[row] * ws;
#pragma unroll
            for (int n = 0; n < 4; ++n) {
                const int col = bcol + n * 64 + wc * 16 + l16;
                out[(size_t)row * OUT_F + col] = (float)acc[m][n][jj] * sc + bias[col];
            }
        }
    }
#undef STAGE_A
#undef READ_A
#undef LOAD_BN
#undef MFMA16
#undef FENCE
#undef KTILE
}

extern "C" void kernel_launch(void* const* d_in, const int* in_sizes, int n_in,
                              void* d_out, int out_size, void* d_ws, size_t ws_size,
                              hipStream_t stream) {
    const float* x       = (const float*)d_in[0];
    const float* w_t     = (const float*)d_in[1];
    const float* w_scale = (const float*)d_in[2];
    const float* bias    = (const float*)d_in[3];
    float* out = (float*)d_out;

    int8_t* xq     = (int8_t*)d_ws;
    float*  scales = (float*)((char*)d_ws + (size_t)T_ROWS * IN_F);
    int8_t* w8     = (int8_t*)((char*)d_ws + (size_t)T_ROWS * IN_F + T_ROWS * sizeof(float));

    prep_kernel<<<T_ROWS + (OUT_F * IN_F) / (16 * 256), 256, 0, stream>>>(
        x, xq, scales, w_t, w8);

    gemm_kernel<<<(T_ROWS / 256) * (OUT_F / 256), 512, 0, stream>>>(
        xq, w8, scales, bias, w_scale, out);
}